// Round 11
// baseline (813.131 us; speedup 1.0000x reference)
//
#include <hip/hip_runtime.h>

constexpr int H = 1024, W = 1024, FID = 100, NF = 8;
constexpr int NPTS = 1 << 20, KSTEPS = 20;
constexpr int HW = H * W;

constexpr int NTX = 16, NTY = 32, NTILES = NTX * NTY;       // 512 tiles (64x32 px)
constexpr int TPIX = 64 * 32;                               // 2048 px/tile
constexpr int NBLK = 1024;                                  // phase blocks
constexpr int PPB = NPTS / NBLK;                            // 1024 points/block
constexpr int PPT = PPB / 256;                              // 4 points/thread
constexpr int SEG_N = NTILES * NBLK;                        // 524,288 segments
constexpr int CHUNK = 32768;                                // records per accum WG
constexpr int TH    = 4096;                                 // dense-tile threshold
constexpr int MAXREC = NPTS * KSTEPS;                       // 20,971,520
constexpr int K4_GRID = MAXREC / CHUNK;                     // 640
constexpr int MAXVIS = K4_GRID + NTILES;                    // 1152 slot cap
constexpr unsigned INV = 0xFFFFFFFFu;

typedef float v2f __attribute__((ext_vector_type(2)));

__device__ __forceinline__ void pk_atomic_add(float* addr, float a, float b) {
#if __has_builtin(__builtin_amdgcn_global_atomic_fadd_v2f32)
    v2f v = {a, b};
    __builtin_amdgcn_global_atomic_fadd_v2f32(
        (__attribute__((address_space(1))) v2f*)addr, v);
#else
    atomicAdd(addr, a);
    atomicAdd(addr + 1, b);
#endif
}

// ---------- K1: count hits per (tile, block); per-thread run cache ----------
__global__ __launch_bounds__(256)
void count_kernel(const float* __restrict__ points,
                  const int* __restrict__ choices,
                  const float* __restrict__ A,
                  const float* __restrict__ b,
                  const float* __restrict__ minv,
                  const float* __restrict__ rangev,
                  const int* __restrict__ skipp,
                  unsigned* __restrict__ hist)
{
    __shared__ float sA[NF * 4], sB[NF * 2];
    __shared__ unsigned shist[4][NTILES];
    const int t = threadIdx.x;
    if (t < NF * 4) sA[t] = A[t];
    if (t < NF * 2) sB[t] = b[t];
    for (int i = t; i < 4 * NTILES; i += 256) ((unsigned*)shist)[i] = 0u;
    __syncthreads();

    const int blk = blockIdx.x;
    const int base = blk * PPB;
    const float mx = minv[0], my = minv[1], rx = rangev[0], ry = rangev[1];
    const int skip = skipp[0];
    const int wv = t >> 6;

    for (int p = 0; p < PPT; ++p) {
        const int n = base + p * 256 + t;
        float x = points[3 * n], y = points[3 * n + 1];
        unsigned ctile = INV, ccnt = 0;
        for (int k = 0; k < KSTEPS; ++k) {
            const int idx = choices[k * NPTS + n];
            const float nx = sA[idx*4+0]*x + sA[idx*4+1]*y + sB[idx*2+0];
            const float ny = sA[idx*4+2]*x + sA[idx*4+3]*y + sB[idx*2+1];
            x = nx; y = ny;
            const int xb = (int)((nx - mx) * rx);
            const int yb = (int)((ny - my) * ry);
            if (k >= skip && (unsigned)xb < (unsigned)W && (unsigned)yb < (unsigned)H) {
                const unsigned tile = (unsigned)(((xb >> 6) << 5) | (yb >> 5));
                if (tile == ctile) { ++ccnt; }
                else {
                    if (ctile != INV) atomicAdd(&shist[wv][ctile], ccnt);
                    ctile = tile; ccnt = 1;
                }
            }
        }
        if (ctile != INV) atomicAdd(&shist[wv][ctile], ccnt);
    }
    __syncthreads();
    for (int tt = t; tt < NTILES; tt += 256)
        hist[tt * NBLK + blk] =
            shist[0][tt] + shist[1][tt] + shist[2][tt] + shist[3][tt];
}

// ---------- K2a: per-1024-chunk exclusive scan (in place); 1 chunk == 1 tile ----------
__global__ __launch_bounds__(1024)
void scan1_kernel(unsigned* __restrict__ hist, unsigned* __restrict__ sums)
{
    __shared__ unsigned buf[2][1024];
    const int t = threadIdx.x;
    const int base = blockIdx.x * 1024;
    const unsigned v = hist[base + t];
    int src = 0;
    buf[0][t] = v; __syncthreads();
    for (int off = 1; off < 1024; off <<= 1) {
        unsigned val = buf[src][t];
        if (t >= off) val += buf[src][t - off];
        buf[1 - src][t] = val; src ^= 1; __syncthreads();
    }
    const unsigned incl = buf[src][t];
    hist[base + t] = incl - v;
    if (t == 1023) sums[blockIdx.x] = incl;
}

// ---------- K2b (tier1): 3 scans — global starts, dense starts, visit offsets ----------
__global__ __launch_bounds__(512)
void scan2v_kernel(unsigned* __restrict__ sums,
                   unsigned* __restrict__ dstart,
                   unsigned* __restrict__ vstart)
{
    __shared__ unsigned buf[2][512];
    const int t = threadIdx.x;
    const unsigned len = sums[t];

    // scan 1: global record starts
    int src = 0;
    buf[0][t] = len; __syncthreads();
    for (int off = 1; off < 512; off <<= 1) {
        unsigned val = buf[src][t];
        if (t >= off) val += buf[src][t - off];
        buf[1 - src][t] = val; src ^= 1; __syncthreads();
    }
    unsigned incl = buf[src][t];
    sums[t] = incl - len;
    if (t == 511) sums[512] = incl;

    // scan 2: dense-domain starts
    const unsigned dlen = (len >= (unsigned)TH) ? len : 0u;
    __syncthreads();
    buf[0][t] = dlen; src = 0; __syncthreads();
    for (int off = 1; off < 512; off <<= 1) {
        unsigned val = buf[src][t];
        if (t >= off) val += buf[src][t - off];
        buf[1 - src][t] = val; src ^= 1; __syncthreads();
    }
    unsigned dincl = buf[src][t];
    const unsigned dexcl = dincl - dlen;
    dstart[t] = dexcl;
    if (t == 511) dstart[512] = dincl;

    // scan 3: visit offsets (chunks of the dense domain overlapped by this tile)
    unsigned c = 0;
    if (dlen) c = (dexcl + dlen - 1) / CHUNK - dexcl / CHUNK + 1;
    __syncthreads();
    buf[0][t] = c; src = 0; __syncthreads();
    for (int off = 1; off < 512; off <<= 1) {
        unsigned val = buf[src][t];
        if (t >= off) val += buf[src][t - off];
        buf[1 - src][t] = val; src ^= 1; __syncthreads();
    }
    unsigned vincl = buf[src][t];
    vstart[t] = vincl - c;
    if (t == 511) vstart[512] = vincl;
}

// ---------- K2b (tier2): plain tile-sum scan ----------
__global__ __launch_bounds__(512)
void scan2_kernel(unsigned* __restrict__ sums)
{
    __shared__ unsigned buf[2][512];
    const int t = threadIdx.x;
    const unsigned v = sums[t];
    int src = 0;
    buf[0][t] = v; __syncthreads();
    for (int off = 1; off < 512; off <<= 1) {
        unsigned val = buf[src][t];
        if (t >= off) val += buf[src][t - off];
        buf[1 - src][t] = val; src ^= 1; __syncthreads();
    }
    const unsigned incl = buf[src][t];
    sums[t] = incl - v;
    if (t == 511) sums[512] = incl;
}

// ---------- K3: scatter records into tile-contiguous segments ----------
__global__ __launch_bounds__(256)
void scatter_kernel(const float* __restrict__ points,
                    const int* __restrict__ choices,
                    const float* __restrict__ A,
                    const float* __restrict__ b,
                    const float* __restrict__ fc,
                    const float* __restrict__ minv,
                    const float* __restrict__ rangev,
                    const int* __restrict__ skipp,
                    const unsigned* __restrict__ scanb,   // = hist after scan
                    const unsigned* __restrict__ sums,
                    uint2* __restrict__ records)
{
    __shared__ float sA[NF * 4], sB[NF * 2], sFC[NF];
    __shared__ unsigned sCur[NTILES];
    const int t = threadIdx.x;
    const int blk = blockIdx.x;
    if (t < NF * 4) sA[t] = A[t];
    if (t < NF * 2) sB[t] = b[t];
    if (t < NF)     sFC[t] = fc[t];
    for (int tt = t; tt < NTILES; tt += 256)
        sCur[tt] = scanb[tt * NBLK + blk] + sums[tt];
    __syncthreads();

    const int base = blk * PPB;
    const float mx = minv[0], my = minv[1], rx = rangev[0], ry = rangev[1];
    const int skip = skipp[0];

    for (int p = 0; p < PPT; ++p) {
        const int n = base + p * 256 + t;
        float x = points[3*n], y = points[3*n+1], c = points[3*n+2];
        for (int k = 0; k < KSTEPS; ++k) {
            const int idx = choices[k * NPTS + n];
            const float nx = sA[idx*4+0]*x + sA[idx*4+1]*y + sB[idx*2+0];
            const float ny = sA[idx*4+2]*x + sA[idx*4+3]*y + sB[idx*2+1];
            c = 0.5f * (c + sFC[idx]);
            x = nx; y = ny;
            const int xb = (int)((nx - mx) * rx);
            const int yb = (int)((ny - my) * ry);
            if (k >= skip && (unsigned)xb < (unsigned)W && (unsigned)yb < (unsigned)H) {
                const int tile = ((xb >> 6) << 5) | (yb >> 5);
                const unsigned pos = atomicAdd(&sCur[tile], 1u);
                records[pos] = make_uint2((unsigned)(((xb & 63) << 5) | (yb & 31)),
                                          __float_as_uint(c));
            }
        }
    }
}

// ---------- K4 (tier1): dense-tile LDS accumulate, butterfly pixel dedup ----------
__global__ __launch_bounds__(256)
void accum_slot_kernel(const uint2* __restrict__ records,
                       const unsigned* __restrict__ sums,
                       const unsigned* __restrict__ dstart,
                       const unsigned* __restrict__ vstart,
                       const float* __restrict__ palette,
                       float* __restrict__ slots)
{
    __shared__ float img[4][TPIX];          // 32 KB
    __shared__ float4 sPal[FID + 1];
    __shared__ unsigned tstart[NTILES + 1];
    __shared__ unsigned dst[NTILES + 1];
    __shared__ unsigned vst[NTILES];
    const int t = threadIdx.x;
    const int lane = t & 63;
    for (int i = t; i < NTILES + 1; i += 256) { tstart[i] = sums[i]; dst[i] = dstart[i]; }
    for (int i = t; i < NTILES; i += 256) vst[i] = vstart[i];
    for (int i = t; i < (FID + 1) * 4; i += 256) ((float*)sPal)[i] = palette[i];
    __syncthreads();

    const unsigned dtotal = dst[NTILES];
    const unsigned r0 = (unsigned)blockIdx.x * CHUNK;
    if (r0 >= dtotal) return;
    const unsigned r1 = min(r0 + (unsigned)CHUNK, dtotal);

    // last tile with dst[tile] <= r0
    int lo = 0, hi = NTILES;
    while (lo < hi) {
        const int mid = (lo + hi + 1) >> 1;
        if (dst[mid] <= r0) lo = mid; else hi = mid - 1;
    }

    for (int tile = lo; tile < NTILES && dst[tile] < r1; ++tile) {
        const unsigned sd = max(dst[tile], r0);
        const unsigned ed = min(dst[tile + 1], r1);
        if (sd >= ed) continue;                 // sparse tiles: dst[t]==dst[t+1]
        const unsigned gs = tstart[tile] + (sd - dst[tile]);
        const unsigned ge = gs + (ed - sd);

        {   // zero LDS image with float4 stores
            float4* im = (float4*)img;
            const float4 z = {0.f, 0.f, 0.f, 0.f};
            for (int i = t; i < TPIX; i += 256) im[i] = z;
        }
        __syncthreads();

        for (unsigned i0 = gs; i0 < ge; i0 += 256) {
            const unsigned i = i0 + t;
            unsigned pix = INV;
            float v0 = 0.f, v1 = 0.f, v2 = 0.f, v3 = 0.f;
            if (i < ge) {
                const uint2 r = records[i];
                pix = r.x;
                const float c = __uint_as_float(r.y);
                const float _c = c * (float)FID;
                const float cf = floorf(_c);
                const float tt = _c - cf;
                const int cfi = (int)fminf(fmaxf(cf, 0.f), (float)FID);
                const int cci = (int)fminf(fmaxf(ceilf(_c), 0.f), (float)FID);
                const float4 pc = sPal[cci];
                const float4 pf = sPal[cfi];
                const float omt = 1.f - tt;
                v0 = tt * pc.x + omt * pf.x;
                v1 = tt * pc.y + omt * pf.y;
                v2 = tt * pc.z + omt * pf.z;
                v3 = tt * pc.w + omt * pf.w;
            }
            // butterfly merge of equal pixels within the wave:
            // collapses the 64-way same-address atomic replay on hot pixels
#pragma unroll
            for (int d = 1; d < 64; d <<= 1) {
                const unsigned opix = __shfl_xor(pix, d, 64);
                const float o0 = __shfl_xor(v0, d, 64);
                const float o1 = __shfl_xor(v1, d, 64);
                const float o2 = __shfl_xor(v2, d, 64);
                const float o3 = __shfl_xor(v3, d, 64);
                if (opix == pix && pix != INV) {
                    if ((lane & d) == 0) { v0 += o0; v1 += o1; v2 += o2; v3 += o3; }
                    else { pix = INV; }
                }
            }
            if (pix != INV) {
                atomicAdd(&img[0][pix], v0);
                atomicAdd(&img[1][pix], v1);
                atomicAdd(&img[2][pix], v2);
                atomicAdd(&img[3][pix], v3);
            }
        }
        __syncthreads();

        // flush: plain coalesced float4 stores to this visit's slot
        const unsigned slot = vst[tile] + ((unsigned)blockIdx.x - dst[tile] / CHUNK);
        float4* sp = (float4*)(slots + (size_t)slot * (4 * TPIX));
        const float4* im = (const float4*)img;
        for (int i = t; i < TPIX; i += 256)
            sp[i] = im[i];
        __syncthreads();
    }
}

// ---------- K5 (tier1): per-tile reduce of slots + sparse records (+raw0) -> out ----------
__global__ __launch_bounds__(256)
void reduce_kernel(const float* __restrict__ slots,
                   const unsigned* __restrict__ vstart,
                   const unsigned* __restrict__ sums,
                   const uint2* __restrict__ records,
                   const float* __restrict__ palette,
                   const float* __restrict__ raw0,
                   float* __restrict__ out)
{
    __shared__ float lds[4][256];           // 4 KB sparse accumulator
    __shared__ float4 sPal[FID + 1];
    const int T = blockIdx.x >> 3;          // tile
    const int g = blockIdx.x & 7;           // 256-px group
    const int t = threadIdx.x;
    for (int i = t; i < (FID + 1) * 4; i += 256) ((float*)sPal)[i] = palette[i];
    ((float*)lds)[t] = 0.f; ((float*)lds)[t + 256] = 0.f;
    ((float*)lds)[t + 512] = 0.f; ((float*)lds)[t + 768] = 0.f;
    __syncthreads();

    const unsigned v0 = vstart[T], v1 = vstart[T + 1];
    const unsigned s = sums[T], e = sums[T + 1];
    const int ch = t >> 6;
    const int f4 = ch * (TPIX / 4) + (g * 256 >> 2) + (t & 63);   // float4 idx in slot

    float4 acc = {0.f, 0.f, 0.f, 0.f};
    for (unsigned v = v0; v < v1; ++v) {
        const float4 sv = ((const float4*)(slots + (size_t)v * (4 * TPIX)))[f4];
        acc.x += sv.x; acc.y += sv.y; acc.z += sv.z; acc.w += sv.w;
    }

    if (v0 == v1 && e > s) {
        // sparse tile: accumulate this block's pixel group directly
        for (unsigned i = s + t; i < e; i += 256) {
            const uint2 r = records[i];
            const int pix = (int)r.x;
            if ((pix >> 8) == g) {
                const float c = __uint_as_float(r.y);
                const float _c = c * (float)FID;
                const float cf = floorf(_c);
                const float tt = _c - cf;
                const int cfi = (int)fminf(fmaxf(cf, 0.f), (float)FID);
                const int cci = (int)fminf(fmaxf(ceilf(_c), 0.f), (float)FID);
                const float4 pc = sPal[cci];
                const float4 pf = sPal[cfi];
                const float omt = 1.f - tt;
                const int lp = pix & 255;
                atomicAdd(&lds[0][lp], tt * pc.x + omt * pf.x);
                atomicAdd(&lds[1][lp], tt * pc.y + omt * pf.y);
                atomicAdd(&lds[2][lp], tt * pc.z + omt * pf.z);
                atomicAdd(&lds[3][lp], tt * pc.w + omt * pf.w);
            }
        }
    }
    __syncthreads();

    const int lbase = (t & 63) * 4;
    acc.x += lds[ch][lbase + 0];
    acc.y += lds[ch][lbase + 1];
    acc.z += lds[ch][lbase + 2];
    acc.w += lds[ch][lbase + 3];

    const int lpix = g * 256 + lbase;
    const int px = lpix >> 5, py = lpix & 31;
    const int tx = T >> 5, ty = T & 31;
    const size_t o = (size_t)ch * HW + (size_t)(tx * 64 + px) * W + (ty * 32 + py);
    const float4 r = *(const float4*)(raw0 + o);
    acc.x += r.x; acc.y += r.y; acc.z += r.z; acc.w += r.w;
    *(float4*)(out + o) = acc;
}

// ---------- K4 (tier2): accum with pk-atomic flush ----------
__global__ __launch_bounds__(256)
void accum_kernel(const uint2* __restrict__ records,
                  const unsigned* __restrict__ sums,
                  const float* __restrict__ palette,
                  float* __restrict__ out)
{
    __shared__ float img[4][TPIX];
    __shared__ float4 sPal[FID + 1];
    __shared__ unsigned tstart[NTILES + 1];
    const int t = threadIdx.x;
    for (int i = t; i < NTILES + 1; i += 256) tstart[i] = sums[i];
    for (int i = t; i < (FID + 1) * 4; i += 256) ((float*)sPal)[i] = palette[i];
    __syncthreads();

    const unsigned total = tstart[NTILES];
    const unsigned r0 = (unsigned)blockIdx.x * CHUNK;
    if (r0 >= total) return;
    const unsigned r1 = min(r0 + (unsigned)CHUNK, total);

    int lo = 0, hi = NTILES;
    while (lo < hi) {
        const int mid = (lo + hi + 1) >> 1;
        if (tstart[mid] <= r0) lo = mid; else hi = mid - 1;
    }

    for (int tile = lo; tile < NTILES && tstart[tile] < r1; ++tile) {
        const unsigned s = max(tstart[tile], r0);
        const unsigned e = min(tstart[tile + 1], r1);
        if (s >= e) continue;

        for (int i = t; i < 4 * TPIX; i += 256) ((float*)img)[i] = 0.f;
        __syncthreads();

        for (unsigned i = s + t; i < e; i += 256) {
            const uint2 r = records[i];
            const int pix = (int)r.x;
            const float c = __uint_as_float(r.y);
            const float _c = c * (float)FID;
            const float cf = floorf(_c);
            const float tt = _c - cf;
            const int cfi = (int)fminf(fmaxf(cf, 0.f), (float)FID);
            const int cci = (int)fminf(fmaxf(ceilf(_c), 0.f), (float)FID);
            const float4 pc = sPal[cci];
            const float4 pf = sPal[cfi];
            const float omt = 1.f - tt;
            atomicAdd(&img[0][pix], tt * pc.x + omt * pf.x);
            atomicAdd(&img[1][pix], tt * pc.y + omt * pf.y);
            atomicAdd(&img[2][pix], tt * pc.z + omt * pf.z);
            atomicAdd(&img[3][pix], tt * pc.w + omt * pf.w);
        }
        __syncthreads();

        const int tx = tile >> 5, ty = tile & 31;
        for (int ch = 0; ch < 4; ++ch) {
            for (int i = t; i < TPIX / 2; i += 256) {
                const int p2 = i * 2;
                const float v0 = img[ch][p2], v1 = img[ch][p2 + 1];
                if (v0 != 0.f || v1 != 0.f) {
                    const int px = p2 >> 5, py = p2 & 31;
                    float* q = out + (size_t)ch * HW + (tx * 64 + px) * W + (ty * 32 + py);
                    pk_atomic_add(q, v0, v1);
                }
            }
        }
        __syncthreads();
    }
}

// ---------- Fallback: direct planar atomics ----------
__global__ __launch_bounds__(256)
void flame_kernel_planar(const float* __restrict__ points,
                         const int* __restrict__ choices,
                         const float* __restrict__ A,
                         const float* __restrict__ b,
                         const float* __restrict__ fc,
                         const float* __restrict__ palette,
                         const float* __restrict__ min_vec,
                         const float* __restrict__ range_vec,
                         const int* __restrict__ skipp,
                         float* __restrict__ out)
{
    __shared__ float sA[NF * 4];
    __shared__ float sB[NF * 2];
    __shared__ float sFC[NF];
    __shared__ float4 sPal[FID + 1];
    const int t = threadIdx.x;
    if (t < NF * 4) sA[t] = A[t];
    if (t < NF * 2) sB[t] = b[t];
    if (t < NF)     sFC[t] = fc[t];
    for (int i = t; i < (FID + 1) * 4; i += 256) ((float*)sPal)[i] = palette[i];
    __syncthreads();

    const int n = blockIdx.x * 256 + t;
    float x = points[3 * n], y = points[3 * n + 1], c = points[3 * n + 2];
    const float mx = min_vec[0], my = min_vec[1];
    const float rx = range_vec[0], ry = range_vec[1];
    const int skip = skipp[0];

    for (int k = 0; k < KSTEPS; ++k) {
        const int idx = choices[k * NPTS + n];
        const float nx = sA[idx*4+0]*x + sA[idx*4+1]*y + sB[idx*2+0];
        const float ny = sA[idx*4+2]*x + sA[idx*4+3]*y + sB[idx*2+1];
        c = 0.5f * (c + sFC[idx]);
        x = nx; y = ny;
        const float _c = c * (float)FID;
        const float cf = floorf(_c);
        const float tt = _c - cf;
        const int cfi = (int)fminf(fmaxf(cf, 0.f), (float)FID);
        const int cci = (int)fminf(fmaxf(ceilf(_c), 0.f), (float)FID);
        const float4 pc = sPal[cci];
        const float4 pf = sPal[cfi];
        const int xb = (int)((nx - mx) * rx);
        const int yb = (int)((ny - my) * ry);
        if (k >= skip && (unsigned)xb < (unsigned)W && (unsigned)yb < (unsigned)H) {
            const int p = xb * W + yb;
            const float omt = 1.f - tt;
            atomicAdd(out + p + 0 * HW, tt * pc.x + omt * pf.x);
            atomicAdd(out + p + 1 * HW, tt * pc.y + omt * pf.y);
            atomicAdd(out + p + 2 * HW, tt * pc.z + omt * pf.z);
            atomicAdd(out + p + 3 * HW, tt * pc.w + omt * pf.w);
        }
    }
}

extern "C" void kernel_launch(void* const* d_in, const int* in_sizes, int n_in,
                              void* d_out, int out_size, void* d_ws, size_t ws_size,
                              hipStream_t stream) {
    const float* points    = (const float*)d_in[0];
    const int*   choices   = (const int*)d_in[1];
    const float* A         = (const float*)d_in[2];
    const float* b         = (const float*)d_in[3];
    const float* fc        = (const float*)d_in[4];
    const float* palette   = (const float*)d_in[5];
    const float* min_vec   = (const float*)d_in[6];
    const float* range_vec = (const float*)d_in[7];
    const float* raw0      = (const float*)d_in[8];
    const int*   skipp     = (const int*)d_in[9];
    float* out = (float*)d_out;
    const size_t img_bytes = (size_t)4 * HW * sizeof(float);   // 16 MB

    const size_t hist_off = 0;                                  // 2 MiB
    const size_t rec_off  = (size_t)SEG_N * 4;
    const size_t rec_cap  = (size_t)MAXREC * 8;                 // 160 MiB
    const size_t sums_off = rec_off + rec_cap;
    const size_t dst_off  = sums_off + 4096;
    const size_t vst_off  = dst_off + 4096;
    const size_t slot_off = vst_off + 4096;
    const size_t slot_cap = (size_t)MAXVIS * (4 * TPIX) * sizeof(float);  // 36.9 MB
    const size_t need1    = slot_off + slot_cap;               // ~209 MB
    const size_t need2    = sums_off + 4096;                   // ~170 MB

    unsigned* hist = (unsigned*)((char*)d_ws + hist_off);
    unsigned* sums = (unsigned*)((char*)d_ws + sums_off);
    uint2*    recs = (uint2*)((char*)d_ws + rec_off);

    if (ws_size >= need1) {
        unsigned* dstart = (unsigned*)((char*)d_ws + dst_off);
        unsigned* vstart = (unsigned*)((char*)d_ws + vst_off);
        float*    slots  = (float*)((char*)d_ws + slot_off);

        count_kernel<<<NBLK, 256, 0, stream>>>(
            points, choices, A, b, min_vec, range_vec, skipp, hist);
        scan1_kernel<<<SEG_N / 1024, 1024, 0, stream>>>(hist, sums);
        scan2v_kernel<<<1, 512, 0, stream>>>(sums, dstart, vstart);
        scatter_kernel<<<NBLK, 256, 0, stream>>>(
            points, choices, A, b, fc, min_vec, range_vec, skipp, hist, sums, recs);
        accum_slot_kernel<<<K4_GRID, 256, 0, stream>>>(
            recs, sums, dstart, vstart, palette, slots);
        reduce_kernel<<<NTILES * 8, 256, 0, stream>>>(
            slots, vstart, sums, recs, palette, raw0, out);
    } else if (ws_size >= need2) {
        hipMemcpyAsync(out, raw0, img_bytes, hipMemcpyDeviceToDevice, stream);
        count_kernel<<<NBLK, 256, 0, stream>>>(
            points, choices, A, b, min_vec, range_vec, skipp, hist);
        scan1_kernel<<<SEG_N / 1024, 1024, 0, stream>>>(hist, sums);
        scan2_kernel<<<1, 512, 0, stream>>>(sums);
        scatter_kernel<<<NBLK, 256, 0, stream>>>(
            points, choices, A, b, fc, min_vec, range_vec, skipp, hist, sums, recs);
        accum_kernel<<<K4_GRID, 256, 0, stream>>>(recs, sums, palette, out);
    } else {
        hipMemcpyAsync(out, raw0, img_bytes, hipMemcpyDeviceToDevice, stream);
        flame_kernel_planar<<<NPTS / 256, 256, 0, stream>>>(
            points, choices, A, b, fc, palette, min_vec, range_vec, skipp, out);
    }
}

// Round 12
// 732.306 us; speedup vs baseline: 1.1104x; 1.1104x over previous
//
#include <hip/hip_runtime.h>

constexpr int H = 1024, W = 1024, FID = 100, NF = 8;
constexpr int NPTS = 1 << 20, KSTEPS = 20;
constexpr int HW = H * W;

constexpr int NTX = 16, NTY = 32, NTILES = NTX * NTY;       // 512 tiles (64x32 px)
constexpr int TPIX = 64 * 32;                               // 2048 px/tile
constexpr int NBLK = 1024;                                  // phase blocks
constexpr int PPB = NPTS / NBLK;                            // 1024 points/block
constexpr int PPT = PPB / 256;                              // 4 points/thread
constexpr int SEG_N = NTILES * NBLK;                        // 524,288 segments
constexpr int CHUNK = 32768;                                // records per accum WG
constexpr int TH    = 4096;                                 // dense-tile threshold
constexpr int MAXREC = NPTS * KSTEPS;                       // 20,971,520
constexpr int K4_GRID = MAXREC / CHUNK;                     // 640
constexpr int K4_BS  = 512;                                 // accum block size
constexpr int MAXVIS = K4_GRID + NTILES;                    // 1152 slot cap
constexpr unsigned INV = 0xFFFFFFFFu;

typedef float v2f __attribute__((ext_vector_type(2)));

__device__ __forceinline__ void pk_atomic_add(float* addr, float a, float b) {
#if __has_builtin(__builtin_amdgcn_global_atomic_fadd_v2f32)
    v2f v = {a, b};
    __builtin_amdgcn_global_atomic_fadd_v2f32(
        (__attribute__((address_space(1))) v2f*)addr, v);
#else
    atomicAdd(addr, a);
    atomicAdd(addr + 1, b);
#endif
}

// ---------- K1: count hits per (tile, block); per-thread run cache ----------
__global__ __launch_bounds__(256)
void count_kernel(const float* __restrict__ points,
                  const int* __restrict__ choices,
                  const float* __restrict__ A,
                  const float* __restrict__ b,
                  const float* __restrict__ minv,
                  const float* __restrict__ rangev,
                  const int* __restrict__ skipp,
                  unsigned* __restrict__ hist)
{
    __shared__ float sA[NF * 4], sB[NF * 2];
    __shared__ unsigned shist[4][NTILES];
    const int t = threadIdx.x;
    if (t < NF * 4) sA[t] = A[t];
    if (t < NF * 2) sB[t] = b[t];
    for (int i = t; i < 4 * NTILES; i += 256) ((unsigned*)shist)[i] = 0u;
    __syncthreads();

    const int blk = blockIdx.x;
    const int base = blk * PPB;
    const float mx = minv[0], my = minv[1], rx = rangev[0], ry = rangev[1];
    const int skip = skipp[0];
    const int wv = t >> 6;

    for (int p = 0; p < PPT; ++p) {
        const int n = base + p * 256 + t;
        float x = points[3 * n], y = points[3 * n + 1];
        unsigned ctile = INV, ccnt = 0;
        for (int k = 0; k < KSTEPS; ++k) {
            const int idx = choices[k * NPTS + n];
            const float nx = sA[idx*4+0]*x + sA[idx*4+1]*y + sB[idx*2+0];
            const float ny = sA[idx*4+2]*x + sA[idx*4+3]*y + sB[idx*2+1];
            x = nx; y = ny;
            const int xb = (int)((nx - mx) * rx);
            const int yb = (int)((ny - my) * ry);
            if (k >= skip && (unsigned)xb < (unsigned)W && (unsigned)yb < (unsigned)H) {
                const unsigned tile = (unsigned)(((xb >> 6) << 5) | (yb >> 5));
                if (tile == ctile) { ++ccnt; }
                else {
                    if (ctile != INV) atomicAdd(&shist[wv][ctile], ccnt);
                    ctile = tile; ccnt = 1;
                }
            }
        }
        if (ctile != INV) atomicAdd(&shist[wv][ctile], ccnt);
    }
    __syncthreads();
    for (int tt = t; tt < NTILES; tt += 256)
        hist[tt * NBLK + blk] =
            shist[0][tt] + shist[1][tt] + shist[2][tt] + shist[3][tt];
}

// ---------- K2a: per-1024-chunk exclusive scan (in place); 1 chunk == 1 tile ----------
__global__ __launch_bounds__(1024)
void scan1_kernel(unsigned* __restrict__ hist, unsigned* __restrict__ sums)
{
    __shared__ unsigned buf[2][1024];
    const int t = threadIdx.x;
    const int base = blockIdx.x * 1024;
    const unsigned v = hist[base + t];
    int src = 0;
    buf[0][t] = v; __syncthreads();
    for (int off = 1; off < 1024; off <<= 1) {
        unsigned val = buf[src][t];
        if (t >= off) val += buf[src][t - off];
        buf[1 - src][t] = val; src ^= 1; __syncthreads();
    }
    const unsigned incl = buf[src][t];
    hist[base + t] = incl - v;
    if (t == 1023) sums[blockIdx.x] = incl;
}

// ---------- K2b (tier1): 3 scans — global starts, dense starts, visit offsets ----------
__global__ __launch_bounds__(512)
void scan2v_kernel(unsigned* __restrict__ sums,
                   unsigned* __restrict__ dstart,
                   unsigned* __restrict__ vstart)
{
    __shared__ unsigned buf[2][512];
    const int t = threadIdx.x;
    const unsigned len = sums[t];

    // scan 1: global record starts
    int src = 0;
    buf[0][t] = len; __syncthreads();
    for (int off = 1; off < 512; off <<= 1) {
        unsigned val = buf[src][t];
        if (t >= off) val += buf[src][t - off];
        buf[1 - src][t] = val; src ^= 1; __syncthreads();
    }
    unsigned incl = buf[src][t];
    sums[t] = incl - len;
    if (t == 511) sums[512] = incl;

    // scan 2: dense-domain starts
    const unsigned dlen = (len >= (unsigned)TH) ? len : 0u;
    __syncthreads();
    buf[0][t] = dlen; src = 0; __syncthreads();
    for (int off = 1; off < 512; off <<= 1) {
        unsigned val = buf[src][t];
        if (t >= off) val += buf[src][t - off];
        buf[1 - src][t] = val; src ^= 1; __syncthreads();
    }
    unsigned dincl = buf[src][t];
    const unsigned dexcl = dincl - dlen;
    dstart[t] = dexcl;
    if (t == 511) dstart[512] = dincl;

    // scan 3: visit offsets (chunks of the dense domain overlapped by this tile)
    unsigned c = 0;
    if (dlen) c = (dexcl + dlen - 1) / CHUNK - dexcl / CHUNK + 1;
    __syncthreads();
    buf[0][t] = c; src = 0; __syncthreads();
    for (int off = 1; off < 512; off <<= 1) {
        unsigned val = buf[src][t];
        if (t >= off) val += buf[src][t - off];
        buf[1 - src][t] = val; src ^= 1; __syncthreads();
    }
    unsigned vincl = buf[src][t];
    vstart[t] = vincl - c;
    if (t == 511) vstart[512] = vincl;
}

// ---------- K2b (tier2): plain tile-sum scan ----------
__global__ __launch_bounds__(512)
void scan2_kernel(unsigned* __restrict__ sums)
{
    __shared__ unsigned buf[2][512];
    const int t = threadIdx.x;
    const unsigned v = sums[t];
    int src = 0;
    buf[0][t] = v; __syncthreads();
    for (int off = 1; off < 512; off <<= 1) {
        unsigned val = buf[src][t];
        if (t >= off) val += buf[src][t - off];
        buf[1 - src][t] = val; src ^= 1; __syncthreads();
    }
    const unsigned incl = buf[src][t];
    sums[t] = incl - v;
    if (t == 511) sums[512] = incl;
}

// ---------- K3: scatter records into tile-contiguous segments ----------
__global__ __launch_bounds__(256)
void scatter_kernel(const float* __restrict__ points,
                    const int* __restrict__ choices,
                    const float* __restrict__ A,
                    const float* __restrict__ b,
                    const float* __restrict__ fc,
                    const float* __restrict__ minv,
                    const float* __restrict__ rangev,
                    const int* __restrict__ skipp,
                    const unsigned* __restrict__ scanb,   // = hist after scan
                    const unsigned* __restrict__ sums,
                    uint2* __restrict__ records)
{
    __shared__ float sA[NF * 4], sB[NF * 2], sFC[NF];
    __shared__ unsigned sCur[NTILES];
    const int t = threadIdx.x;
    const int blk = blockIdx.x;
    if (t < NF * 4) sA[t] = A[t];
    if (t < NF * 2) sB[t] = b[t];
    if (t < NF)     sFC[t] = fc[t];
    for (int tt = t; tt < NTILES; tt += 256)
        sCur[tt] = scanb[tt * NBLK + blk] + sums[tt];
    __syncthreads();

    const int base = blk * PPB;
    const float mx = minv[0], my = minv[1], rx = rangev[0], ry = rangev[1];
    const int skip = skipp[0];

    for (int p = 0; p < PPT; ++p) {
        const int n = base + p * 256 + t;
        float x = points[3*n], y = points[3*n+1], c = points[3*n+2];
        for (int k = 0; k < KSTEPS; ++k) {
            const int idx = choices[k * NPTS + n];
            const float nx = sA[idx*4+0]*x + sA[idx*4+1]*y + sB[idx*2+0];
            const float ny = sA[idx*4+2]*x + sA[idx*4+3]*y + sB[idx*2+1];
            c = 0.5f * (c + sFC[idx]);
            x = nx; y = ny;
            const int xb = (int)((nx - mx) * rx);
            const int yb = (int)((ny - my) * ry);
            if (k >= skip && (unsigned)xb < (unsigned)W && (unsigned)yb < (unsigned)H) {
                const int tile = ((xb >> 6) << 5) | (yb >> 5);
                const unsigned pos = atomicAdd(&sCur[tile], 1u);
                records[pos] = make_uint2((unsigned)(((xb & 63) << 5) | (yb & 31)),
                                          __float_as_uint(c));
            }
        }
    }
}

// ---------- K4 (tier1): dense-tile LDS accumulate, 512 thr + SW-pipelined loads ----------
__global__ __launch_bounds__(K4_BS)
void accum_slot_kernel(const uint2* __restrict__ records,
                       const unsigned* __restrict__ sums,
                       const unsigned* __restrict__ dstart,
                       const unsigned* __restrict__ vstart,
                       const float* __restrict__ palette,
                       float* __restrict__ slots)
{
    __shared__ float img[4][TPIX];          // 32 KB
    __shared__ float4 sPal[FID + 1];
    __shared__ unsigned tstart[NTILES + 1];
    __shared__ unsigned dst[NTILES + 1];
    __shared__ unsigned vst[NTILES];
    const int t = threadIdx.x;
    for (int i = t; i < NTILES + 1; i += K4_BS) { tstart[i] = sums[i]; dst[i] = dstart[i]; }
    for (int i = t; i < NTILES; i += K4_BS) vst[i] = vstart[i];
    for (int i = t; i < (FID + 1) * 4; i += K4_BS) ((float*)sPal)[i] = palette[i];
    __syncthreads();

    const unsigned dtotal = dst[NTILES];
    const unsigned r0 = (unsigned)blockIdx.x * CHUNK;
    if (r0 >= dtotal) return;
    const unsigned r1 = min(r0 + (unsigned)CHUNK, dtotal);

    // last tile with dst[tile] <= r0
    int lo = 0, hi = NTILES;
    while (lo < hi) {
        const int mid = (lo + hi + 1) >> 1;
        if (dst[mid] <= r0) lo = mid; else hi = mid - 1;
    }

    for (int tile = lo; tile < NTILES && dst[tile] < r1; ++tile) {
        const unsigned sd = max(dst[tile], r0);
        const unsigned ed = min(dst[tile + 1], r1);
        if (sd >= ed) continue;                 // sparse tiles: dst[t]==dst[t+1]
        const unsigned gs = tstart[tile] + (sd - dst[tile]);
        const unsigned ge = gs + (ed - sd);

        {   // zero LDS image with float4 stores
            float4* im = (float4*)img;
            const float4 z = {0.f, 0.f, 0.f, 0.f};
            for (int i = t; i < TPIX; i += K4_BS) im[i] = z;
        }
        __syncthreads();

        // software-pipelined record loop: prefetch next while processing cur
        unsigned cpix = INV;
        float a0 = 0.f, a1 = 0.f, a2 = 0.f, a3 = 0.f;

        unsigned i = gs + t;
        bool valid = (i < ge);
        uint2 r = valid ? records[i] : make_uint2(0u, 0u);
        while (valid) {
            const unsigned inext = i + K4_BS;
            const bool vnext = (inext < ge);
            uint2 rn = vnext ? records[inext] : make_uint2(0u, 0u);

            const int pix = (int)r.x;
            const float c = __uint_as_float(r.y);
            const float _c = c * (float)FID;
            const float cf = floorf(_c);
            const float tt = _c - cf;
            const int cfi = (int)fminf(fmaxf(cf, 0.f), (float)FID);
            const int cci = (int)fminf(fmaxf(ceilf(_c), 0.f), (float)FID);
            const float4 pc = sPal[cci];
            const float4 pf = sPal[cfi];
            const float omt = 1.f - tt;
            const float v0 = tt * pc.x + omt * pf.x;
            const float v1 = tt * pc.y + omt * pf.y;
            const float v2 = tt * pc.z + omt * pf.z;
            const float v3 = tt * pc.w + omt * pf.w;
            if ((unsigned)pix == cpix) {
                a0 += v0; a1 += v1; a2 += v2; a3 += v3;
            } else {
                if (cpix != INV) {
                    atomicAdd(&img[0][cpix], a0);
                    atomicAdd(&img[1][cpix], a1);
                    atomicAdd(&img[2][cpix], a2);
                    atomicAdd(&img[3][cpix], a3);
                }
                cpix = (unsigned)pix;
                a0 = v0; a1 = v1; a2 = v2; a3 = v3;
            }

            r = rn; i = inext; valid = vnext;
        }
        if (cpix != INV) {
            atomicAdd(&img[0][cpix], a0);
            atomicAdd(&img[1][cpix], a1);
            atomicAdd(&img[2][cpix], a2);
            atomicAdd(&img[3][cpix], a3);
        }
        __syncthreads();

        // flush: plain coalesced float4 stores to this visit's slot
        const unsigned slot = vst[tile] + ((unsigned)blockIdx.x - dst[tile] / CHUNK);
        float4* sp = (float4*)(slots + (size_t)slot * (4 * TPIX));
        const float4* im = (const float4*)img;
        for (int i2 = t; i2 < TPIX; i2 += K4_BS)
            sp[i2] = im[i2];
        __syncthreads();
    }
}

// ---------- K5 (tier1): per-tile reduce of slots + sparse records (+raw0) -> out ----------
__global__ __launch_bounds__(256)
void reduce_kernel(const float* __restrict__ slots,
                   const unsigned* __restrict__ vstart,
                   const unsigned* __restrict__ sums,
                   const uint2* __restrict__ records,
                   const float* __restrict__ palette,
                   const float* __restrict__ raw0,
                   float* __restrict__ out)
{
    __shared__ float lds[4][256];           // 4 KB sparse accumulator
    __shared__ float4 sPal[FID + 1];
    const int T = blockIdx.x >> 3;          // tile
    const int g = blockIdx.x & 7;           // 256-px group
    const int t = threadIdx.x;
    for (int i = t; i < (FID + 1) * 4; i += 256) ((float*)sPal)[i] = palette[i];
    ((float*)lds)[t] = 0.f; ((float*)lds)[t + 256] = 0.f;
    ((float*)lds)[t + 512] = 0.f; ((float*)lds)[t + 768] = 0.f;
    __syncthreads();

    const unsigned v0 = vstart[T], v1 = vstart[T + 1];
    const unsigned s = sums[T], e = sums[T + 1];
    const int ch = t >> 6;
    const int f4 = ch * (TPIX / 4) + (g * 256 >> 2) + (t & 63);   // float4 idx in slot

    float4 acc = {0.f, 0.f, 0.f, 0.f};
    for (unsigned v = v0; v < v1; ++v) {
        const float4 sv = ((const float4*)(slots + (size_t)v * (4 * TPIX)))[f4];
        acc.x += sv.x; acc.y += sv.y; acc.z += sv.z; acc.w += sv.w;
    }

    if (v0 == v1 && e > s) {
        // sparse tile: accumulate this block's pixel group directly
        for (unsigned i = s + t; i < e; i += 256) {
            const uint2 r = records[i];
            const int pix = (int)r.x;
            if ((pix >> 8) == g) {
                const float c = __uint_as_float(r.y);
                const float _c = c * (float)FID;
                const float cf = floorf(_c);
                const float tt = _c - cf;
                const int cfi = (int)fminf(fmaxf(cf, 0.f), (float)FID);
                const int cci = (int)fminf(fmaxf(ceilf(_c), 0.f), (float)FID);
                const float4 pc = sPal[cci];
                const float4 pf = sPal[cfi];
                const float omt = 1.f - tt;
                const int lp = pix & 255;
                atomicAdd(&lds[0][lp], tt * pc.x + omt * pf.x);
                atomicAdd(&lds[1][lp], tt * pc.y + omt * pf.y);
                atomicAdd(&lds[2][lp], tt * pc.z + omt * pf.z);
                atomicAdd(&lds[3][lp], tt * pc.w + omt * pf.w);
            }
        }
    }
    __syncthreads();

    const int lbase = (t & 63) * 4;
    acc.x += lds[ch][lbase + 0];
    acc.y += lds[ch][lbase + 1];
    acc.z += lds[ch][lbase + 2];
    acc.w += lds[ch][lbase + 3];

    const int lpix = g * 256 + lbase;
    const int px = lpix >> 5, py = lpix & 31;
    const int tx = T >> 5, ty = T & 31;
    const size_t o = (size_t)ch * HW + (size_t)(tx * 64 + px) * W + (ty * 32 + py);
    const float4 r = *(const float4*)(raw0 + o);
    acc.x += r.x; acc.y += r.y; acc.z += r.z; acc.w += r.w;
    *(float4*)(out + o) = acc;
}

// ---------- K4 (tier2): accum with pk-atomic flush ----------
__global__ __launch_bounds__(256)
void accum_kernel(const uint2* __restrict__ records,
                  const unsigned* __restrict__ sums,
                  const float* __restrict__ palette,
                  float* __restrict__ out)
{
    __shared__ float img[4][TPIX];
    __shared__ float4 sPal[FID + 1];
    __shared__ unsigned tstart[NTILES + 1];
    const int t = threadIdx.x;
    for (int i = t; i < NTILES + 1; i += 256) tstart[i] = sums[i];
    for (int i = t; i < (FID + 1) * 4; i += 256) ((float*)sPal)[i] = palette[i];
    __syncthreads();

    const unsigned total = tstart[NTILES];
    const unsigned r0 = (unsigned)blockIdx.x * CHUNK;
    if (r0 >= total) return;
    const unsigned r1 = min(r0 + (unsigned)CHUNK, total);

    int lo = 0, hi = NTILES;
    while (lo < hi) {
        const int mid = (lo + hi + 1) >> 1;
        if (tstart[mid] <= r0) lo = mid; else hi = mid - 1;
    }

    for (int tile = lo; tile < NTILES && tstart[tile] < r1; ++tile) {
        const unsigned s = max(tstart[tile], r0);
        const unsigned e = min(tstart[tile + 1], r1);
        if (s >= e) continue;

        for (int i = t; i < 4 * TPIX; i += 256) ((float*)img)[i] = 0.f;
        __syncthreads();

        for (unsigned i = s + t; i < e; i += 256) {
            const uint2 r = records[i];
            const int pix = (int)r.x;
            const float c = __uint_as_float(r.y);
            const float _c = c * (float)FID;
            const float cf = floorf(_c);
            const float tt = _c - cf;
            const int cfi = (int)fminf(fmaxf(cf, 0.f), (float)FID);
            const int cci = (int)fminf(fmaxf(ceilf(_c), 0.f), (float)FID);
            const float4 pc = sPal[cci];
            const float4 pf = sPal[cfi];
            const float omt = 1.f - tt;
            atomicAdd(&img[0][pix], tt * pc.x + omt * pf.x);
            atomicAdd(&img[1][pix], tt * pc.y + omt * pf.y);
            atomicAdd(&img[2][pix], tt * pc.z + omt * pf.z);
            atomicAdd(&img[3][pix], tt * pc.w + omt * pf.w);
        }
        __syncthreads();

        const int tx = tile >> 5, ty = tile & 31;
        for (int ch = 0; ch < 4; ++ch) {
            for (int i = t; i < TPIX / 2; i += 256) {
                const int p2 = i * 2;
                const float v0 = img[ch][p2], v1 = img[ch][p2 + 1];
                if (v0 != 0.f || v1 != 0.f) {
                    const int px = p2 >> 5, py = p2 & 31;
                    float* q = out + (size_t)ch * HW + (tx * 64 + px) * W + (ty * 32 + py);
                    pk_atomic_add(q, v0, v1);
                }
            }
        }
        __syncthreads();
    }
}

// ---------- Fallback: direct planar atomics ----------
__global__ __launch_bounds__(256)
void flame_kernel_planar(const float* __restrict__ points,
                         const int* __restrict__ choices,
                         const float* __restrict__ A,
                         const float* __restrict__ b,
                         const float* __restrict__ fc,
                         const float* __restrict__ palette,
                         const float* __restrict__ min_vec,
                         const float* __restrict__ range_vec,
                         const int* __restrict__ skipp,
                         float* __restrict__ out)
{
    __shared__ float sA[NF * 4];
    __shared__ float sB[NF * 2];
    __shared__ float sFC[NF];
    __shared__ float4 sPal[FID + 1];
    const int t = threadIdx.x;
    if (t < NF * 4) sA[t] = A[t];
    if (t < NF * 2) sB[t] = b[t];
    if (t < NF)     sFC[t] = fc[t];
    for (int i = t; i < (FID + 1) * 4; i += 256) ((float*)sPal)[i] = palette[i];
    __syncthreads();

    const int n = blockIdx.x * 256 + t;
    float x = points[3 * n], y = points[3 * n + 1], c = points[3 * n + 2];
    const float mx = min_vec[0], my = min_vec[1];
    const float rx = range_vec[0], ry = range_vec[1];
    const int skip = skipp[0];

    for (int k = 0; k < KSTEPS; ++k) {
        const int idx = choices[k * NPTS + n];
        const float nx = sA[idx*4+0]*x + sA[idx*4+1]*y + sB[idx*2+0];
        const float ny = sA[idx*4+2]*x + sA[idx*4+3]*y + sB[idx*2+1];
        c = 0.5f * (c + sFC[idx]);
        x = nx; y = ny;
        const float _c = c * (float)FID;
        const float cf = floorf(_c);
        const float tt = _c - cf;
        const int cfi = (int)fminf(fmaxf(cf, 0.f), (float)FID);
        const int cci = (int)fminf(fmaxf(ceilf(_c), 0.f), (float)FID);
        const float4 pc = sPal[cci];
        const float4 pf = sPal[cfi];
        const int xb = (int)((nx - mx) * rx);
        const int yb = (int)((ny - my) * ry);
        if (k >= skip && (unsigned)xb < (unsigned)W && (unsigned)yb < (unsigned)H) {
            const int p = xb * W + yb;
            const float omt = 1.f - tt;
            atomicAdd(out + p + 0 * HW, tt * pc.x + omt * pf.x);
            atomicAdd(out + p + 1 * HW, tt * pc.y + omt * pf.y);
            atomicAdd(out + p + 2 * HW, tt * pc.z + omt * pf.z);
            atomicAdd(out + p + 3 * HW, tt * pc.w + omt * pf.w);
        }
    }
}

extern "C" void kernel_launch(void* const* d_in, const int* in_sizes, int n_in,
                              void* d_out, int out_size, void* d_ws, size_t ws_size,
                              hipStream_t stream) {
    const float* points    = (const float*)d_in[0];
    const int*   choices   = (const int*)d_in[1];
    const float* A         = (const float*)d_in[2];
    const float* b         = (const float*)d_in[3];
    const float* fc        = (const float*)d_in[4];
    const float* palette   = (const float*)d_in[5];
    const float* min_vec   = (const float*)d_in[6];
    const float* range_vec = (const float*)d_in[7];
    const float* raw0      = (const float*)d_in[8];
    const int*   skipp     = (const int*)d_in[9];
    float* out = (float*)d_out;
    const size_t img_bytes = (size_t)4 * HW * sizeof(float);   // 16 MB

    const size_t hist_off = 0;                                  // 2 MiB
    const size_t rec_off  = (size_t)SEG_N * 4;
    const size_t rec_cap  = (size_t)MAXREC * 8;                 // 160 MiB
    const size_t sums_off = rec_off + rec_cap;
    const size_t dst_off  = sums_off + 4096;
    const size_t vst_off  = dst_off + 4096;
    const size_t slot_off = vst_off + 4096;
    const size_t slot_cap = (size_t)MAXVIS * (4 * TPIX) * sizeof(float);  // 36.9 MB
    const size_t need1    = slot_off + slot_cap;               // ~209 MB
    const size_t need2    = sums_off + 4096;                   // ~170 MB

    unsigned* hist = (unsigned*)((char*)d_ws + hist_off);
    unsigned* sums = (unsigned*)((char*)d_ws + sums_off);
    uint2*    recs = (uint2*)((char*)d_ws + rec_off);

    if (ws_size >= need1) {
        unsigned* dstart = (unsigned*)((char*)d_ws + dst_off);
        unsigned* vstart = (unsigned*)((char*)d_ws + vst_off);
        float*    slots  = (float*)((char*)d_ws + slot_off);

        count_kernel<<<NBLK, 256, 0, stream>>>(
            points, choices, A, b, min_vec, range_vec, skipp, hist);
        scan1_kernel<<<SEG_N / 1024, 1024, 0, stream>>>(hist, sums);
        scan2v_kernel<<<1, 512, 0, stream>>>(sums, dstart, vstart);
        scatter_kernel<<<NBLK, 256, 0, stream>>>(
            points, choices, A, b, fc, min_vec, range_vec, skipp, hist, sums, recs);
        accum_slot_kernel<<<K4_GRID, K4_BS, 0, stream>>>(
            recs, sums, dstart, vstart, palette, slots);
        reduce_kernel<<<NTILES * 8, 256, 0, stream>>>(
            slots, vstart, sums, recs, palette, raw0, out);
    } else if (ws_size >= need2) {
        hipMemcpyAsync(out, raw0, img_bytes, hipMemcpyDeviceToDevice, stream);
        count_kernel<<<NBLK, 256, 0, stream>>>(
            points, choices, A, b, min_vec, range_vec, skipp, hist);
        scan1_kernel<<<SEG_N / 1024, 1024, 0, stream>>>(hist, sums);
        scan2_kernel<<<1, 512, 0, stream>>>(sums);
        scatter_kernel<<<NBLK, 256, 0, stream>>>(
            points, choices, A, b, fc, min_vec, range_vec, skipp, hist, sums, recs);
        accum_kernel<<<K4_GRID, 256, 0, stream>>>(recs, sums, palette, out);
    } else {
        hipMemcpyAsync(out, raw0, img_bytes, hipMemcpyDeviceToDevice, stream);
        flame_kernel_planar<<<NPTS / 256, 256, 0, stream>>>(
            points, choices, A, b, fc, palette, min_vec, range_vec, skipp, out);
    }
}

// Round 13
// 715.403 us; speedup vs baseline: 1.1366x; 1.0236x over previous
//
#include <hip/hip_runtime.h>

constexpr int H = 1024, W = 1024, FID = 100, NF = 8;
constexpr int NPTS = 1 << 20, KSTEPS = 20;
constexpr int HW = H * W;

constexpr int NTX = 16, NTY = 32, NTILES = NTX * NTY;       // 512 tiles (64x32 px)
constexpr int TPIX = 64 * 32;                               // 2048 px/tile
constexpr int NBLK = 1024;                                  // phase blocks
constexpr int PPB = NPTS / NBLK;                            // 1024 points/block
constexpr int PPT = PPB / 256;                              // 4 points/thread
constexpr int SEG_N = NTILES * NBLK;                        // 524,288 segments
constexpr int CHUNK = 32768;                                // records per accum WG
constexpr int TH    = 4096;                                 // dense-tile threshold
constexpr int MAXREC = NPTS * KSTEPS;                       // 20,971,520
constexpr int K4_GRID = MAXREC / CHUNK;                     // 640
constexpr int K4_BS  = 512;                                 // accum block size
constexpr int MAXVIS = K4_GRID + NTILES;                    // 1152 slot cap
constexpr unsigned INV = 0xFFFFFFFFu;
constexpr float QSCALE = 16384.0f;                          // _c fixed-point scale
constexpr float QINV   = 1.0f / 16384.0f;

typedef float v2f __attribute__((ext_vector_type(2)));

__device__ __forceinline__ void pk_atomic_add(float* addr, float a, float b) {
#if __has_builtin(__builtin_amdgcn_global_atomic_fadd_v2f32)
    v2f v = {a, b};
    __builtin_amdgcn_global_atomic_fadd_v2f32(
        (__attribute__((address_space(1))) v2f*)addr, v);
#else
    atomicAdd(addr, a);
    atomicAdd(addr + 1, b);
#endif
}

// decode packed record -> 4 channel values + local pixel
__device__ __forceinline__ void decode_rec(unsigned r, const float4* sPal,
                                           int& pix, float& v0, float& v1,
                                           float& v2, float& v3) {
    pix = (int)(r & 2047u);
    const float _c = (float)(r >> 11) * QINV;       // = c * 100, quantized
    const float cf = floorf(_c);
    const float tt = _c - cf;
    const int cfi = (int)fminf(fmaxf(cf, 0.f), (float)FID);
    const int cci = (int)fminf(fmaxf(ceilf(_c), 0.f), (float)FID);
    const float4 pc = sPal[cci];
    const float4 pf = sPal[cfi];
    const float omt = 1.f - tt;
    v0 = tt * pc.x + omt * pf.x;
    v1 = tt * pc.y + omt * pf.y;
    v2 = tt * pc.z + omt * pf.z;
    v3 = tt * pc.w + omt * pf.w;
}

// ---------- K1: count hits per (tile, block); per-thread run cache ----------
__global__ __launch_bounds__(256)
void count_kernel(const float* __restrict__ points,
                  const int* __restrict__ choices,
                  const float* __restrict__ A,
                  const float* __restrict__ b,
                  const float* __restrict__ minv,
                  const float* __restrict__ rangev,
                  const int* __restrict__ skipp,
                  unsigned* __restrict__ hist)
{
    __shared__ float sA[NF * 4], sB[NF * 2];
    __shared__ unsigned shist[4][NTILES];
    const int t = threadIdx.x;
    if (t < NF * 4) sA[t] = A[t];
    if (t < NF * 2) sB[t] = b[t];
    for (int i = t; i < 4 * NTILES; i += 256) ((unsigned*)shist)[i] = 0u;
    __syncthreads();

    const int blk = blockIdx.x;
    const int base = blk * PPB;
    const float mx = minv[0], my = minv[1], rx = rangev[0], ry = rangev[1];
    const int skip = skipp[0];
    const int wv = t >> 6;

    for (int p = 0; p < PPT; ++p) {
        const int n = base + p * 256 + t;
        float x = points[3 * n], y = points[3 * n + 1];
        unsigned ctile = INV, ccnt = 0;
        for (int k = 0; k < KSTEPS; ++k) {
            const int idx = choices[k * NPTS + n];
            const float nx = sA[idx*4+0]*x + sA[idx*4+1]*y + sB[idx*2+0];
            const float ny = sA[idx*4+2]*x + sA[idx*4+3]*y + sB[idx*2+1];
            x = nx; y = ny;
            const int xb = (int)((nx - mx) * rx);
            const int yb = (int)((ny - my) * ry);
            if (k >= skip && (unsigned)xb < (unsigned)W && (unsigned)yb < (unsigned)H) {
                const unsigned tile = (unsigned)(((xb >> 6) << 5) | (yb >> 5));
                if (tile == ctile) { ++ccnt; }
                else {
                    if (ctile != INV) atomicAdd(&shist[wv][ctile], ccnt);
                    ctile = tile; ccnt = 1;
                }
            }
        }
        if (ctile != INV) atomicAdd(&shist[wv][ctile], ccnt);
    }
    __syncthreads();
    for (int tt = t; tt < NTILES; tt += 256)
        hist[tt * NBLK + blk] =
            shist[0][tt] + shist[1][tt] + shist[2][tt] + shist[3][tt];
}

// ---------- K2a: per-1024-chunk exclusive scan (in place); 1 chunk == 1 tile ----------
__global__ __launch_bounds__(1024)
void scan1_kernel(unsigned* __restrict__ hist, unsigned* __restrict__ sums)
{
    __shared__ unsigned buf[2][1024];
    const int t = threadIdx.x;
    const int base = blockIdx.x * 1024;
    const unsigned v = hist[base + t];
    int src = 0;
    buf[0][t] = v; __syncthreads();
    for (int off = 1; off < 1024; off <<= 1) {
        unsigned val = buf[src][t];
        if (t >= off) val += buf[src][t - off];
        buf[1 - src][t] = val; src ^= 1; __syncthreads();
    }
    const unsigned incl = buf[src][t];
    hist[base + t] = incl - v;
    if (t == 1023) sums[blockIdx.x] = incl;
}

// ---------- K2b (tier1): 3 scans — global starts, dense starts, visit offsets ----------
__global__ __launch_bounds__(512)
void scan2v_kernel(unsigned* __restrict__ sums,
                   unsigned* __restrict__ dstart,
                   unsigned* __restrict__ vstart)
{
    __shared__ unsigned buf[2][512];
    const int t = threadIdx.x;
    const unsigned len = sums[t];

    int src = 0;
    buf[0][t] = len; __syncthreads();
    for (int off = 1; off < 512; off <<= 1) {
        unsigned val = buf[src][t];
        if (t >= off) val += buf[src][t - off];
        buf[1 - src][t] = val; src ^= 1; __syncthreads();
    }
    unsigned incl = buf[src][t];
    sums[t] = incl - len;
    if (t == 511) sums[512] = incl;

    const unsigned dlen = (len >= (unsigned)TH) ? len : 0u;
    __syncthreads();
    buf[0][t] = dlen; src = 0; __syncthreads();
    for (int off = 1; off < 512; off <<= 1) {
        unsigned val = buf[src][t];
        if (t >= off) val += buf[src][t - off];
        buf[1 - src][t] = val; src ^= 1; __syncthreads();
    }
    unsigned dincl = buf[src][t];
    const unsigned dexcl = dincl - dlen;
    dstart[t] = dexcl;
    if (t == 511) dstart[512] = dincl;

    unsigned c = 0;
    if (dlen) c = (dexcl + dlen - 1) / CHUNK - dexcl / CHUNK + 1;
    __syncthreads();
    buf[0][t] = c; src = 0; __syncthreads();
    for (int off = 1; off < 512; off <<= 1) {
        unsigned val = buf[src][t];
        if (t >= off) val += buf[src][t - off];
        buf[1 - src][t] = val; src ^= 1; __syncthreads();
    }
    unsigned vincl = buf[src][t];
    vstart[t] = vincl - c;
    if (t == 511) vstart[512] = vincl;
}

// ---------- K2b (tier2): plain tile-sum scan ----------
__global__ __launch_bounds__(512)
void scan2_kernel(unsigned* __restrict__ sums)
{
    __shared__ unsigned buf[2][512];
    const int t = threadIdx.x;
    const unsigned v = sums[t];
    int src = 0;
    buf[0][t] = v; __syncthreads();
    for (int off = 1; off < 512; off <<= 1) {
        unsigned val = buf[src][t];
        if (t >= off) val += buf[src][t - off];
        buf[1 - src][t] = val; src ^= 1; __syncthreads();
    }
    const unsigned incl = buf[src][t];
    sums[t] = incl - v;
    if (t == 511) sums[512] = incl;
}

// ---------- K3: scatter packed 4B records into tile-contiguous segments ----------
__global__ __launch_bounds__(256)
void scatter_kernel(const float* __restrict__ points,
                    const int* __restrict__ choices,
                    const float* __restrict__ A,
                    const float* __restrict__ b,
                    const float* __restrict__ fc,
                    const float* __restrict__ minv,
                    const float* __restrict__ rangev,
                    const int* __restrict__ skipp,
                    const unsigned* __restrict__ scanb,   // = hist after scan
                    const unsigned* __restrict__ sums,
                    unsigned* __restrict__ records)
{
    __shared__ float sA[NF * 4], sB[NF * 2], sFC[NF];
    __shared__ unsigned sCur[NTILES];
    const int t = threadIdx.x;
    const int blk = blockIdx.x;
    if (t < NF * 4) sA[t] = A[t];
    if (t < NF * 2) sB[t] = b[t];
    if (t < NF)     sFC[t] = fc[t];
    for (int tt = t; tt < NTILES; tt += 256)
        sCur[tt] = scanb[tt * NBLK + blk] + sums[tt];
    __syncthreads();

    const int base = blk * PPB;
    const float mx = minv[0], my = minv[1], rx = rangev[0], ry = rangev[1];
    const int skip = skipp[0];

    for (int p = 0; p < PPT; ++p) {
        const int n = base + p * 256 + t;
        float x = points[3*n], y = points[3*n+1], c = points[3*n+2];
        for (int k = 0; k < KSTEPS; ++k) {
            const int idx = choices[k * NPTS + n];
            const float nx = sA[idx*4+0]*x + sA[idx*4+1]*y + sB[idx*2+0];
            const float ny = sA[idx*4+2]*x + sA[idx*4+3]*y + sB[idx*2+1];
            c = 0.5f * (c + sFC[idx]);
            x = nx; y = ny;
            const int xb = (int)((nx - mx) * rx);
            const int yb = (int)((ny - my) * ry);
            if (k >= skip && (unsigned)xb < (unsigned)W && (unsigned)yb < (unsigned)H) {
                const int tile = ((xb >> 6) << 5) | (yb >> 5);
                const unsigned pos = atomicAdd(&sCur[tile], 1u);
                // pack: q (21b fixed-point of c*100) << 11 | local pixel (11b)
                const unsigned q = (unsigned)__float2int_rn(c * (100.0f * QSCALE));
                records[pos] = (q << 11) | (unsigned)(((xb & 63) << 5) | (yb & 31));
            }
        }
    }
}

// ---------- K4 (tier1): dense-tile LDS accumulate, 2 records/thread/iter ----------
__global__ __launch_bounds__(K4_BS)
void accum_slot_kernel(const unsigned* __restrict__ records,
                       const unsigned* __restrict__ sums,
                       const unsigned* __restrict__ dstart,
                       const unsigned* __restrict__ vstart,
                       const float* __restrict__ palette,
                       float* __restrict__ slots)
{
    __shared__ float img[4][TPIX];          // 32 KB
    __shared__ float4 sPal[FID + 1];
    __shared__ unsigned tstart[NTILES + 1];
    __shared__ unsigned dst[NTILES + 1];
    __shared__ unsigned vst[NTILES];
    const int t = threadIdx.x;
    for (int i = t; i < NTILES + 1; i += K4_BS) { tstart[i] = sums[i]; dst[i] = dstart[i]; }
    for (int i = t; i < NTILES; i += K4_BS) vst[i] = vstart[i];
    for (int i = t; i < (FID + 1) * 4; i += K4_BS) ((float*)sPal)[i] = palette[i];
    __syncthreads();

    const unsigned dtotal = dst[NTILES];
    const unsigned r0 = (unsigned)blockIdx.x * CHUNK;
    if (r0 >= dtotal) return;
    const unsigned r1 = min(r0 + (unsigned)CHUNK, dtotal);

    int lo = 0, hi = NTILES;
    while (lo < hi) {
        const int mid = (lo + hi + 1) >> 1;
        if (dst[mid] <= r0) lo = mid; else hi = mid - 1;
    }

    for (int tile = lo; tile < NTILES && dst[tile] < r1; ++tile) {
        const unsigned sd = max(dst[tile], r0);
        const unsigned ed = min(dst[tile + 1], r1);
        if (sd >= ed) continue;
        const unsigned gs = tstart[tile] + (sd - dst[tile]);
        const unsigned ge = gs + (ed - sd);

        {
            float4* im = (float4*)img;
            const float4 z = {0.f, 0.f, 0.f, 0.f};
            for (int i = t; i < TPIX; i += K4_BS) im[i] = z;
        }
        __syncthreads();

        // 2 adjacent records per thread per iteration
        unsigned cpix = INV;
        float a0 = 0.f, a1 = 0.f, a2 = 0.f, a3 = 0.f;

        for (unsigned i0 = gs + 2 * t; i0 < ge; i0 += 2 * K4_BS) {
#pragma unroll
            for (int j = 0; j < 2; ++j) {
                const unsigned i = i0 + j;
                if (i >= ge) break;
                int pix; float v0, v1, v2, v3;
                decode_rec(records[i], sPal, pix, v0, v1, v2, v3);
                if ((unsigned)pix == cpix) {
                    a0 += v0; a1 += v1; a2 += v2; a3 += v3;
                } else {
                    if (cpix != INV) {
                        atomicAdd(&img[0][cpix], a0);
                        atomicAdd(&img[1][cpix], a1);
                        atomicAdd(&img[2][cpix], a2);
                        atomicAdd(&img[3][cpix], a3);
                    }
                    cpix = (unsigned)pix;
                    a0 = v0; a1 = v1; a2 = v2; a3 = v3;
                }
            }
        }
        if (cpix != INV) {
            atomicAdd(&img[0][cpix], a0);
            atomicAdd(&img[1][cpix], a1);
            atomicAdd(&img[2][cpix], a2);
            atomicAdd(&img[3][cpix], a3);
        }
        __syncthreads();

        const unsigned slot = vst[tile] + ((unsigned)blockIdx.x - dst[tile] / CHUNK);
        float4* sp = (float4*)(slots + (size_t)slot * (4 * TPIX));
        const float4* im = (const float4*)img;
        for (int i2 = t; i2 < TPIX; i2 += K4_BS)
            sp[i2] = im[i2];
        __syncthreads();
    }
}

// ---------- K5 (tier1): per-tile reduce of slots + sparse records (+raw0) -> out ----------
__global__ __launch_bounds__(256)
void reduce_kernel(const float* __restrict__ slots,
                   const unsigned* __restrict__ vstart,
                   const unsigned* __restrict__ sums,
                   const unsigned* __restrict__ records,
                   const float* __restrict__ palette,
                   const float* __restrict__ raw0,
                   float* __restrict__ out)
{
    __shared__ float lds[4][256];           // 4 KB sparse accumulator
    __shared__ float4 sPal[FID + 1];
    const int T = blockIdx.x >> 3;          // tile
    const int g = blockIdx.x & 7;           // 256-px group
    const int t = threadIdx.x;
    for (int i = t; i < (FID + 1) * 4; i += 256) ((float*)sPal)[i] = palette[i];
    ((float*)lds)[t] = 0.f; ((float*)lds)[t + 256] = 0.f;
    ((float*)lds)[t + 512] = 0.f; ((float*)lds)[t + 768] = 0.f;
    __syncthreads();

    const unsigned v0 = vstart[T], v1 = vstart[T + 1];
    const unsigned s = sums[T], e = sums[T + 1];
    const int ch = t >> 6;
    const int f4 = ch * (TPIX / 4) + (g * 256 >> 2) + (t & 63);

    float4 acc = {0.f, 0.f, 0.f, 0.f};
    for (unsigned v = v0; v < v1; ++v) {
        const float4 sv = ((const float4*)(slots + (size_t)v * (4 * TPIX)))[f4];
        acc.x += sv.x; acc.y += sv.y; acc.z += sv.z; acc.w += sv.w;
    }

    if (v0 == v1 && e > s) {
        for (unsigned i = s + t; i < e; i += 256) {
            const unsigned r = records[i];
            const int pix = (int)(r & 2047u);
            if ((pix >> 8) == g) {
                int dummy; float w0, w1, w2, w3;
                decode_rec(r, sPal, dummy, w0, w1, w2, w3);
                const int lp = pix & 255;
                atomicAdd(&lds[0][lp], w0);
                atomicAdd(&lds[1][lp], w1);
                atomicAdd(&lds[2][lp], w2);
                atomicAdd(&lds[3][lp], w3);
            }
        }
    }
    __syncthreads();

    const int lbase = (t & 63) * 4;
    acc.x += lds[ch][lbase + 0];
    acc.y += lds[ch][lbase + 1];
    acc.z += lds[ch][lbase + 2];
    acc.w += lds[ch][lbase + 3];

    const int lpix = g * 256 + lbase;
    const int px = lpix >> 5, py = lpix & 31;
    const int tx = T >> 5, ty = T & 31;
    const size_t o = (size_t)ch * HW + (size_t)(tx * 64 + px) * W + (ty * 32 + py);
    const float4 r = *(const float4*)(raw0 + o);
    acc.x += r.x; acc.y += r.y; acc.z += r.z; acc.w += r.w;
    *(float4*)(out + o) = acc;
}

// ---------- K4 (tier2): accum with pk-atomic flush (4B records) ----------
__global__ __launch_bounds__(256)
void accum_kernel(const unsigned* __restrict__ records,
                  const unsigned* __restrict__ sums,
                  const float* __restrict__ palette,
                  float* __restrict__ out)
{
    __shared__ float img[4][TPIX];
    __shared__ float4 sPal[FID + 1];
    __shared__ unsigned tstart[NTILES + 1];
    const int t = threadIdx.x;
    for (int i = t; i < NTILES + 1; i += 256) tstart[i] = sums[i];
    for (int i = t; i < (FID + 1) * 4; i += 256) ((float*)sPal)[i] = palette[i];
    __syncthreads();

    const unsigned total = tstart[NTILES];
    const unsigned r0 = (unsigned)blockIdx.x * CHUNK;
    if (r0 >= total) return;
    const unsigned r1 = min(r0 + (unsigned)CHUNK, total);

    int lo = 0, hi = NTILES;
    while (lo < hi) {
        const int mid = (lo + hi + 1) >> 1;
        if (tstart[mid] <= r0) lo = mid; else hi = mid - 1;
    }

    for (int tile = lo; tile < NTILES && tstart[tile] < r1; ++tile) {
        const unsigned s = max(tstart[tile], r0);
        const unsigned e = min(tstart[tile + 1], r1);
        if (s >= e) continue;

        for (int i = t; i < 4 * TPIX; i += 256) ((float*)img)[i] = 0.f;
        __syncthreads();

        for (unsigned i = s + t; i < e; i += 256) {
            int pix; float v0, v1, v2, v3;
            decode_rec(records[i], sPal, pix, v0, v1, v2, v3);
            atomicAdd(&img[0][pix], v0);
            atomicAdd(&img[1][pix], v1);
            atomicAdd(&img[2][pix], v2);
            atomicAdd(&img[3][pix], v3);
        }
        __syncthreads();

        const int tx = tile >> 5, ty = tile & 31;
        for (int ch = 0; ch < 4; ++ch) {
            for (int i = t; i < TPIX / 2; i += 256) {
                const int p2 = i * 2;
                const float v0 = img[ch][p2], v1 = img[ch][p2 + 1];
                if (v0 != 0.f || v1 != 0.f) {
                    const int px = p2 >> 5, py = p2 & 31;
                    float* q = out + (size_t)ch * HW + (tx * 64 + px) * W + (ty * 32 + py);
                    pk_atomic_add(q, v0, v1);
                }
            }
        }
        __syncthreads();
    }
}

// ---------- Fallback: direct planar atomics ----------
__global__ __launch_bounds__(256)
void flame_kernel_planar(const float* __restrict__ points,
                         const int* __restrict__ choices,
                         const float* __restrict__ A,
                         const float* __restrict__ b,
                         const float* __restrict__ fc,
                         const float* __restrict__ palette,
                         const float* __restrict__ min_vec,
                         const float* __restrict__ range_vec,
                         const int* __restrict__ skipp,
                         float* __restrict__ out)
{
    __shared__ float sA[NF * 4];
    __shared__ float sB[NF * 2];
    __shared__ float sFC[NF];
    __shared__ float4 sPal[FID + 1];
    const int t = threadIdx.x;
    if (t < NF * 4) sA[t] = A[t];
    if (t < NF * 2) sB[t] = b[t];
    if (t < NF)     sFC[t] = fc[t];
    for (int i = t; i < (FID + 1) * 4; i += 256) ((float*)sPal)[i] = palette[i];
    __syncthreads();

    const int n = blockIdx.x * 256 + t;
    float x = points[3 * n], y = points[3 * n + 1], c = points[3 * n + 2];
    const float mx = min_vec[0], my = min_vec[1];
    const float rx = range_vec[0], ry = range_vec[1];
    const int skip = skipp[0];

    for (int k = 0; k < KSTEPS; ++k) {
        const int idx = choices[k * NPTS + n];
        const float nx = sA[idx*4+0]*x + sA[idx*4+1]*y + sB[idx*2+0];
        const float ny = sA[idx*4+2]*x + sA[idx*4+3]*y + sB[idx*2+1];
        c = 0.5f * (c + sFC[idx]);
        x = nx; y = ny;
        const float _c = c * (float)FID;
        const float cf = floorf(_c);
        const float tt = _c - cf;
        const int cfi = (int)fminf(fmaxf(cf, 0.f), (float)FID);
        const int cci = (int)fminf(fmaxf(ceilf(_c), 0.f), (float)FID);
        const float4 pc = sPal[cci];
        const float4 pf = sPal[cfi];
        const int xb = (int)((nx - mx) * rx);
        const int yb = (int)((ny - my) * ry);
        if (k >= skip && (unsigned)xb < (unsigned)W && (unsigned)yb < (unsigned)H) {
            const int p = xb * W + yb;
            const float omt = 1.f - tt;
            atomicAdd(out + p + 0 * HW, tt * pc.x + omt * pf.x);
            atomicAdd(out + p + 1 * HW, tt * pc.y + omt * pf.y);
            atomicAdd(out + p + 2 * HW, tt * pc.z + omt * pf.z);
            atomicAdd(out + p + 3 * HW, tt * pc.w + omt * pf.w);
        }
    }
}

extern "C" void kernel_launch(void* const* d_in, const int* in_sizes, int n_in,
                              void* d_out, int out_size, void* d_ws, size_t ws_size,
                              hipStream_t stream) {
    const float* points    = (const float*)d_in[0];
    const int*   choices   = (const int*)d_in[1];
    const float* A         = (const float*)d_in[2];
    const float* b         = (const float*)d_in[3];
    const float* fc        = (const float*)d_in[4];
    const float* palette   = (const float*)d_in[5];
    const float* min_vec   = (const float*)d_in[6];
    const float* range_vec = (const float*)d_in[7];
    const float* raw0      = (const float*)d_in[8];
    const int*   skipp     = (const int*)d_in[9];
    float* out = (float*)d_out;
    const size_t img_bytes = (size_t)4 * HW * sizeof(float);   // 16 MB

    const size_t hist_off = 0;                                  // 2 MiB
    const size_t rec_off  = (size_t)SEG_N * 4;
    const size_t rec_cap  = (size_t)MAXREC * 4;                 // 84 MiB (u32 records)
    const size_t sums_off = rec_off + rec_cap;
    const size_t dst_off  = sums_off + 4096;
    const size_t vst_off  = dst_off + 4096;
    const size_t slot_off = vst_off + 4096;
    const size_t slot_cap = (size_t)MAXVIS * (4 * TPIX) * sizeof(float);  // 36.9 MB
    const size_t need1    = slot_off + slot_cap;               // ~123 MB
    const size_t need2    = sums_off + 4096;                   // ~86 MB

    unsigned* hist = (unsigned*)((char*)d_ws + hist_off);
    unsigned* sums = (unsigned*)((char*)d_ws + sums_off);
    unsigned* recs = (unsigned*)((char*)d_ws + rec_off);

    if (ws_size >= need1) {
        unsigned* dstart = (unsigned*)((char*)d_ws + dst_off);
        unsigned* vstart = (unsigned*)((char*)d_ws + vst_off);
        float*    slots  = (float*)((char*)d_ws + slot_off);

        count_kernel<<<NBLK, 256, 0, stream>>>(
            points, choices, A, b, min_vec, range_vec, skipp, hist);
        scan1_kernel<<<SEG_N / 1024, 1024, 0, stream>>>(hist, sums);
        scan2v_kernel<<<1, 512, 0, stream>>>(sums, dstart, vstart);
        scatter_kernel<<<NBLK, 256, 0, stream>>>(
            points, choices, A, b, fc, min_vec, range_vec, skipp, hist, sums, recs);
        accum_slot_kernel<<<K4_GRID, K4_BS, 0, stream>>>(
            recs, sums, dstart, vstart, palette, slots);
        reduce_kernel<<<NTILES * 8, 256, 0, stream>>>(
            slots, vstart, sums, recs, palette, raw0, out);
    } else if (ws_size >= need2) {
        hipMemcpyAsync(out, raw0, img_bytes, hipMemcpyDeviceToDevice, stream);
        count_kernel<<<NBLK, 256, 0, stream>>>(
            points, choices, A, b, min_vec, range_vec, skipp, hist);
        scan1_kernel<<<SEG_N / 1024, 1024, 0, stream>>>(hist, sums);
        scan2_kernel<<<1, 512, 0, stream>>>(sums);
        scatter_kernel<<<NBLK, 256, 0, stream>>>(
            points, choices, A, b, fc, min_vec, range_vec, skipp, hist, sums, recs);
        accum_kernel<<<K4_GRID, 256, 0, stream>>>(recs, sums, palette, out);
    } else {
        hipMemcpyAsync(out, raw0, img_bytes, hipMemcpyDeviceToDevice, stream);
        flame_kernel_planar<<<NPTS / 256, 256, 0, stream>>>(
            points, choices, A, b, fc, palette, min_vec, range_vec, skipp, out);
    }
}